// Round 2
// baseline (250.343 us; speedup 1.0000x reference)
//
#include <hip/hip_runtime.h>
#include <stdint.h>

typedef __attribute__((ext_vector_type(8))) short short8;
typedef __attribute__((ext_vector_type(4))) float floatx4;

#define B_   8
#define H_   16
#define N_   1024
#define D_   64
#define NH_  (B_*H_)
#define LOG2E 1.44269504088896340736f

extern "C" {
__device__ float __ocml_native_exp2_f32(float);
__device__ float __ocml_native_rsqrt_f32(float);
}

// pack two f32 -> bf16x2 (round-half-up on magnitude; fine for our ranges)
__device__ __forceinline__ unsigned int pk2(float a, float b) {
    unsigned int ua = __float_as_uint(a) + 0x8000u;
    unsigned int ub = __float_as_uint(b) + 0x8000u;
    return __builtin_amdgcn_perm(ub, ua, 0x07060302);  // (bf(b)<<16)|bf(a)
}

// ---------------------------------------------------------------------------
// Fully fused cosine attention.
// R2: 1024 threads = 16 waves; wave = 16 queries (1 m-tile); block = 256 q;
// grid = 128 heads * 4 (XCD-swizzled) -> 2 blocks/CU, 32 waves/CU (8/SIMD,
// 100% nominal occupancy; was 4/SIMD = 50%). Staging is split by wave role:
// waves 0-7 stage K, waves 8-15 stage V (same total work, half per thread).
// LDS: stride-64-short rows, XOR swizzle cb^(row&7) on 16B blocks, all
// accesses 16B-aligned b128 (uniform 8 lanes / 16B window = full LDS BW).
//   ks[key][d] : K chunk bf16, row-normalized
//   vt[d][key] : V chunk transposed, key order permuted by
//                L(cb,j) = (cb>>2)*32 + (cb&3)*4 + (j>>2)*16 + (j&3)
// S^T = K.Qn^T via MFMA so exp(S^T) is directly the PV A-fragment.
// T5: s_setprio(1) around MFMA clusters.
// ---------------------------------------------------------------------------
__global__ __launch_bounds__(1024, 8) void attn_fused(
    const float* __restrict__ q, const float* __restrict__ k,
    const float* __restrict__ v, float* __restrict__ out)
{
    __shared__ __align__(16) unsigned short ks[2][64 * 64];
    __shared__ __align__(16) unsigned short vt[2][64 * 64];

    const int bid = blockIdx.x;
    const int xcd = bid & 7, rest = bid >> 3;
    const int qt = rest & 3;
    const int head = (rest >> 2) * 8 + xcd;    // 4 blocks of a head share an XCD
    const int tid = threadIdx.x, w = tid >> 6, lane = tid & 63;
    const int lam = lane & 15, quad = lane >> 4;
    const int sw = lam & 7;                    // frag-read swizzle key
    const int q0 = qt * 256 + w * 16;          // this wave's 16 queries

    const float* qh = q + ((size_t)head * N_ + q0) * D_;
    const float* kh = k + (size_t)head * N_ * D_;
    const float* vh = v + (size_t)head * N_ * D_;

    // ---- Q: load f32, L2-normalize (x log2e), pack to bf16 B-frags ----
    short8 aq[2];
    {
        const float* qr = qh + lam * D_ + quad * 8;
        float4 f0 = *(const float4*)(qr);
        float4 f1 = *(const float4*)(qr + 4);
        float4 f2 = *(const float4*)(qr + 32);
        float4 f3 = *(const float4*)(qr + 36);
        float ss = f0.x*f0.x + f0.y*f0.y + f0.z*f0.z + f0.w*f0.w
                 + f1.x*f1.x + f1.y*f1.y + f1.z*f1.z + f1.w*f1.w
                 + f2.x*f2.x + f2.y*f2.y + f2.z*f2.z + f2.w*f2.w
                 + f3.x*f3.x + f3.y*f3.y + f3.z*f3.z + f3.w*f3.w;
        ss += __shfl_xor(ss, 16);      // 4 quads of same lam cover dims 0..63
        ss += __shfl_xor(ss, 32);
        float sc = LOG2E * __ocml_native_rsqrt_f32(ss);
        union { unsigned int u[4]; short8 s8; } p0, p1;
        p0.u[0] = pk2(f0.x*sc, f0.y*sc); p0.u[1] = pk2(f0.z*sc, f0.w*sc);
        p0.u[2] = pk2(f1.x*sc, f1.y*sc); p0.u[3] = pk2(f1.z*sc, f1.w*sc);
        p1.u[0] = pk2(f2.x*sc, f2.y*sc); p1.u[1] = pk2(f2.z*sc, f2.w*sc);
        p1.u[2] = pk2(f3.x*sc, f3.y*sc); p1.u[3] = pk2(f3.z*sc, f3.w*sc);
        aq[0] = p0.s8; aq[1] = p1.s8;
    }

    floatx4 oacc[4];
    #pragma unroll
    for (int dt = 0; dt < 4; dt++) oacc[dt] = (floatx4){0.f, 0.f, 0.f, 0.f};
    float l = 0.f;

    // ---- staging maps: waves 0-7 stage K, waves 8-15 stage V ----
    const bool krole = (w < 8);
    const int w8 = w & 7;
    // K: thread owns key-row srow, 8 dims at d-block cbk = lane&7
    const int srow = w8 * 8 + (lane >> 3);
    const int cbk  = lane & 7;
    const int ksw  = srow & 7;
    // V^T: thread owns d = lane, phys key-block cb = w8 (8 logical keys)
    const int Lb   = ((w8 >> 2) << 5) + ((w8 & 3) << 2);   // L(w8, 0)
    const int vwin = (w8 ^ (lane & 7)) << 3;

    float4 kx[2];
    float  vr[8];

    auto gload = [&](int ck) {
        if (krole) {
            const float* kp = kh + ((size_t)(ck * 64 + srow)) * D_ + cbk * 8;
            kx[0] = *(const float4*)(kp);
            kx[1] = *(const float4*)(kp + 4);
        } else {
            #pragma unroll
            for (int j = 0; j < 8; j++) {
                int L = Lb + ((j >> 2) << 4) + (j & 3);
                vr[j] = vh[((size_t)(ck * 64 + L)) * D_ + lane];   // coalesced b32
            }
        }
    };

    auto stage = [&](int buf) {
        if (krole) {
            float ss = kx[0].x*kx[0].x + kx[0].y*kx[0].y + kx[0].z*kx[0].z + kx[0].w*kx[0].w
                     + kx[1].x*kx[1].x + kx[1].y*kx[1].y + kx[1].z*kx[1].z + kx[1].w*kx[1].w;
            ss += __shfl_xor(ss, 1);   // 8 lanes of same key cover dims 0..63
            ss += __shfl_xor(ss, 2);
            ss += __shfl_xor(ss, 4);
            float sc = __ocml_native_rsqrt_f32(ss);
            union { unsigned int u[4]; short8 s8; } pk;
            pk.u[0] = pk2(kx[0].x*sc, kx[0].y*sc); pk.u[1] = pk2(kx[0].z*sc, kx[0].w*sc);
            pk.u[2] = pk2(kx[1].x*sc, kx[1].y*sc); pk.u[3] = pk2(kx[1].z*sc, kx[1].w*sc);
            *(short8*)&ks[buf][srow * 64 + ((cbk ^ ksw) << 3)] = pk.s8;      // b128
        } else {
            union { unsigned int u[4]; short8 s8; } pv;
            pv.u[0] = pk2(vr[0], vr[1]); pv.u[1] = pk2(vr[2], vr[3]);
            pv.u[2] = pk2(vr[4], vr[5]); pv.u[3] = pk2(vr[6], vr[7]);
            *(short8*)&vt[buf][lane * 64 + vwin] = pv.s8;                    // b128
        }
    };

    auto compute = [&](int buf) {
        const unsigned short* ksb = &ks[buf][0];
        const unsigned short* vsb = &vt[buf][0];
        #pragma unroll
        for (int g = 0; g < 2; g++) {
            // ---- S^T for 32 keys: A = K-frag (LDS b128), B = Q-frag (regs) ----
            floatx4 s[2];
            #pragma unroll
            for (int s2 = 0; s2 < 2; s2++) {
                int st = g * 2 + s2;
                short8 bk0 = *(const short8*)(ksb + (st * 16 + lam) * 64 + (((0 + quad) ^ sw) << 3));
                short8 bk1 = *(const short8*)(ksb + (st * 16 + lam) * 64 + (((4 + quad) ^ sw) << 3));
                __builtin_amdgcn_s_setprio(1);              // T5: MFMA cluster
                floatx4 acc = (floatx4){0.f, 0.f, 0.f, 0.f};
                acc = __builtin_amdgcn_mfma_f32_16x16x32_bf16(bk0, aq[0], acc, 0, 0, 0);
                acc = __builtin_amdgcn_mfma_f32_16x16x32_bf16(bk1, aq[1], acc, 0, 0, 0);
                s[s2] = acc;
                __builtin_amdgcn_s_setprio(0);              // TRANS/VALU phase next
            }
            // ---- exp2 + pack: S^T C-layout IS the PV A-fragment layout ----
            float e00 = __ocml_native_exp2_f32(s[0][0]);
            float e01 = __ocml_native_exp2_f32(s[0][1]);
            float e02 = __ocml_native_exp2_f32(s[0][2]);
            float e03 = __ocml_native_exp2_f32(s[0][3]);
            float e10 = __ocml_native_exp2_f32(s[1][0]);
            float e11 = __ocml_native_exp2_f32(s[1][1]);
            float e12 = __ocml_native_exp2_f32(s[1][2]);
            float e13 = __ocml_native_exp2_f32(s[1][3]);
            l += ((e00 + e01) + (e02 + e03)) + ((e10 + e11) + (e12 + e13));
            union { unsigned int u[4]; short8 s8; } pk;
            pk.u[0] = pk2(e00, e01); pk.u[1] = pk2(e02, e03);
            pk.u[2] = pk2(e10, e11); pk.u[3] = pk2(e12, e13);
            short8 pa = pk.s8;
            // ---- PV: B-frag = one b128 from vt (permuted V^T) ----
            __builtin_amdgcn_s_setprio(1);                  // T5: MFMA cluster
            #pragma unroll
            for (int dt = 0; dt < 4; dt++) {
                short8 bv = *(const short8*)(vsb + (dt * 16 + lam) * 64 + (((g * 4 + quad) ^ sw) << 3));
                oacc[dt] = __builtin_amdgcn_mfma_f32_16x16x32_bf16(pa, bv, oacc[dt], 0, 0, 0);
            }
            __builtin_amdgcn_s_setprio(0);                  // staging phase next
        }
    };

    // ---- software-pipelined chunk loop: 1 barrier per chunk ----
    gload(0);
    stage(0);
    __syncthreads();
    for (int c = 0; c < 16; ++c) {
        int buf = c & 1;
        if (c < 15) gload(c + 1);      // regs prefetch overlaps compute
        compute(buf);
        if (c < 15) stage(buf ^ 1);    // waits on prefetch, writes other buffer
        __syncthreads();
    }

    // ---- epilogue: reduce l across quads, divide, store f32 ----
    const int b = head >> 4, hh = head & 15;
    {
        float lr = l;
        lr += __shfl_xor(lr, 16);
        lr += __shfl_xor(lr, 32);
        float rl = 1.0f / lr;                    // lane lam holds 1/l for query lam
        float rq[4];
        #pragma unroll
        for (int r = 0; r < 4; r++) rq[r] = __shfl(rl, quad * 4 + r);
        float* ob = out + ((size_t)b * N_ + q0) * (H_ * D_) + hh * 64;
        #pragma unroll
        for (int dt = 0; dt < 4; dt++)
            #pragma unroll
            for (int r = 0; r < 4; r++)
                ob[(quad * 4 + r) * (H_ * D_) + dt * 16 + lam] = oacc[dt][r] * rq[r];
    }
}

extern "C" void kernel_launch(void* const* d_in, const int* in_sizes, int n_in,
                              void* d_out, int out_size, void* d_ws, size_t ws_size,
                              hipStream_t stream) {
    const float* q = (const float*)d_in[0];
    const float* k = (const float*)d_in[1];
    const float* v = (const float*)d_in[2];
    float* out = (float*)d_out;
    (void)d_ws; (void)ws_size;
    hipLaunchKernelGGL(attn_fused, dim3(NH_ * 4), dim3(1024), 0, stream, q, k, v, out);
}

// Round 3
// 194.452 us; speedup vs baseline: 1.2874x; 1.2874x over previous
//
#include <hip/hip_runtime.h>
#include <stdint.h>

typedef __attribute__((ext_vector_type(8))) short short8;
typedef __attribute__((ext_vector_type(4))) float floatx4;

#define B_   8
#define H_   16
#define N_   1024
#define D_   64
#define NH_  (B_*H_)
#define LOG2E 1.44269504088896340736f

extern "C" {
__device__ float __ocml_native_exp2_f32(float);
__device__ float __ocml_native_rsqrt_f32(float);
}

// pack two f32 -> bf16x2 (round-half-up on magnitude; fine for our ranges)
__device__ __forceinline__ unsigned int pk2(float a, float b) {
    unsigned int ua = __float_as_uint(a) + 0x8000u;
    unsigned int ub = __float_as_uint(b) + 0x8000u;
    return __builtin_amdgcn_perm(ub, ua, 0x07060302);  // (bf(b)<<16)|bf(a)
}

// ---------------------------------------------------------------------------
// Fully fused cosine attention.
// R3: 512 threads = 8 waves; wave = 16 queries; block = 128 queries;
// grid = 128 heads * 8 q-tiles (XCD-swizzled) -> 4 blocks/CU, 32 waves/CU
// (8/SIMD, 100% nominal occupancy) at the proven spill-free 64-VGPR point.
// (R2's 1024-thread/launch_bounds(1024,8) variant clamped to 32 VGPR and
// spilled: WRITE_SIZE 59->173 MB, dur 108->160 us. Occupancy must come from
// the grid, not from thread count.)
// LDS: stride-64-short rows, XOR swizzle cb^(row&7) on 16B blocks, all
// accesses 16B-aligned b128 (uniform 8 lanes / 16B window = full LDS BW).
//   ks[key][d] : K chunk bf16, row-normalized
//   vt[d][key] : V chunk transposed, key order permuted by
//                L(cb,j) = (cb>>2)*32 + (cb&3)*4 + (j>>2)*16 + (j&3)
// S^T = K.Qn^T via MFMA so exp(S^T) is directly the PV A-fragment.
// T5: s_setprio(1) around MFMA clusters.
// ---------------------------------------------------------------------------
__global__ __launch_bounds__(512, 8) void attn_fused(
    const float* __restrict__ q, const float* __restrict__ k,
    const float* __restrict__ v, float* __restrict__ out)
{
    __shared__ __align__(16) unsigned short ks[2][64 * 64];
    __shared__ __align__(16) unsigned short vt[2][64 * 64];

    const int bid = blockIdx.x;
    const int xcd = bid & 7, rest = bid >> 3;
    const int qt = rest & 7;                   // 8 q-tiles per head
    const int head = (rest >> 3) * 8 + xcd;    // 8 blocks of a head share an XCD
    const int tid = threadIdx.x, w = tid >> 6, lane = tid & 63;
    const int lam = lane & 15, quad = lane >> 4;
    const int sw = lam & 7;                    // frag-read swizzle key
    const int q0 = qt * 128 + w * 16;          // this wave's 16 queries

    const float* qh = q + ((size_t)head * N_ + q0) * D_;
    const float* kh = k + (size_t)head * N_ * D_;
    const float* vh = v + (size_t)head * N_ * D_;

    // ---- Q: load f32, L2-normalize (x log2e), pack to bf16 B-frags ----
    short8 aq[2];
    {
        const float* qr = qh + lam * D_ + quad * 8;
        float4 f0 = *(const float4*)(qr);
        float4 f1 = *(const float4*)(qr + 4);
        float4 f2 = *(const float4*)(qr + 32);
        float4 f3 = *(const float4*)(qr + 36);
        float ss = f0.x*f0.x + f0.y*f0.y + f0.z*f0.z + f0.w*f0.w
                 + f1.x*f1.x + f1.y*f1.y + f1.z*f1.z + f1.w*f1.w
                 + f2.x*f2.x + f2.y*f2.y + f2.z*f2.z + f2.w*f2.w
                 + f3.x*f3.x + f3.y*f3.y + f3.z*f3.z + f3.w*f3.w;
        ss += __shfl_xor(ss, 16);      // 4 quads of same lam cover dims 0..63
        ss += __shfl_xor(ss, 32);
        float sc = LOG2E * __ocml_native_rsqrt_f32(ss);
        union { unsigned int u[4]; short8 s8; } p0, p1;
        p0.u[0] = pk2(f0.x*sc, f0.y*sc); p0.u[1] = pk2(f0.z*sc, f0.w*sc);
        p0.u[2] = pk2(f1.x*sc, f1.y*sc); p0.u[3] = pk2(f1.z*sc, f1.w*sc);
        p1.u[0] = pk2(f2.x*sc, f2.y*sc); p1.u[1] = pk2(f2.z*sc, f2.w*sc);
        p1.u[2] = pk2(f3.x*sc, f3.y*sc); p1.u[3] = pk2(f3.z*sc, f3.w*sc);
        aq[0] = p0.s8; aq[1] = p1.s8;
    }

    floatx4 oacc[4];
    #pragma unroll
    for (int dt = 0; dt < 4; dt++) oacc[dt] = (floatx4){0.f, 0.f, 0.f, 0.f};
    float l = 0.f;

    // ---- staging maps (all 512 threads stage one 64-key chunk, K and V) ----
    // K: thread owns key-row srow, 8 dims at d-block cbk = lane&7
    const int srow = w * 8 + (lane >> 3);
    const int cbk  = lane & 7;
    const int ksw  = srow & 7;
    // V^T: thread owns d = lane, phys key-block cb = w (8 logical keys)
    const int Lb   = ((w >> 2) << 5) + ((w & 3) << 2);   // L(w, 0)
    const int vwin = (w ^ (lane & 7)) << 3;

    float4 kx[2];
    float  vr[8];

    auto gload = [&](int ck) {
        const float* kp = kh + ((size_t)(ck * 64 + srow)) * D_ + cbk * 8;
        kx[0] = *(const float4*)(kp);
        kx[1] = *(const float4*)(kp + 4);
        #pragma unroll
        for (int j = 0; j < 8; j++) {
            int L = Lb + ((j >> 2) << 4) + (j & 3);
            vr[j] = vh[((size_t)(ck * 64 + L)) * D_ + lane];   // coalesced b32
        }
    };

    auto stage = [&](int buf) {
        float ss = kx[0].x*kx[0].x + kx[0].y*kx[0].y + kx[0].z*kx[0].z + kx[0].w*kx[0].w
                 + kx[1].x*kx[1].x + kx[1].y*kx[1].y + kx[1].z*kx[1].z + kx[1].w*kx[1].w;
        ss += __shfl_xor(ss, 1);       // 8 lanes of same key cover dims 0..63
        ss += __shfl_xor(ss, 2);
        ss += __shfl_xor(ss, 4);
        float sc = __ocml_native_rsqrt_f32(ss);
        union { unsigned int u[4]; short8 s8; } pk;
        pk.u[0] = pk2(kx[0].x*sc, kx[0].y*sc); pk.u[1] = pk2(kx[0].z*sc, kx[0].w*sc);
        pk.u[2] = pk2(kx[1].x*sc, kx[1].y*sc); pk.u[3] = pk2(kx[1].z*sc, kx[1].w*sc);
        *(short8*)&ks[buf][srow * 64 + ((cbk ^ ksw) << 3)] = pk.s8;      // b128
        union { unsigned int u[4]; short8 s8; } pv;
        pv.u[0] = pk2(vr[0], vr[1]); pv.u[1] = pk2(vr[2], vr[3]);
        pv.u[2] = pk2(vr[4], vr[5]); pv.u[3] = pk2(vr[6], vr[7]);
        *(short8*)&vt[buf][lane * 64 + vwin] = pv.s8;                    // b128
    };

    auto compute = [&](int buf) {
        const unsigned short* ksb = &ks[buf][0];
        const unsigned short* vsb = &vt[buf][0];
        #pragma unroll
        for (int g = 0; g < 2; g++) {
            // ---- S^T for 32 keys: A = K-frag (LDS b128), B = Q-frag (regs) ----
            floatx4 s[2];
            #pragma unroll
            for (int s2 = 0; s2 < 2; s2++) {
                int st = g * 2 + s2;
                short8 bk0 = *(const short8*)(ksb + (st * 16 + lam) * 64 + (((0 + quad) ^ sw) << 3));
                short8 bk1 = *(const short8*)(ksb + (st * 16 + lam) * 64 + (((4 + quad) ^ sw) << 3));
                __builtin_amdgcn_s_setprio(1);              // T5: MFMA cluster
                floatx4 acc = (floatx4){0.f, 0.f, 0.f, 0.f};
                acc = __builtin_amdgcn_mfma_f32_16x16x32_bf16(bk0, aq[0], acc, 0, 0, 0);
                acc = __builtin_amdgcn_mfma_f32_16x16x32_bf16(bk1, aq[1], acc, 0, 0, 0);
                s[s2] = acc;
                __builtin_amdgcn_s_setprio(0);              // TRANS/VALU phase next
            }
            // ---- exp2 + pack: S^T C-layout IS the PV A-fragment layout ----
            float e00 = __ocml_native_exp2_f32(s[0][0]);
            float e01 = __ocml_native_exp2_f32(s[0][1]);
            float e02 = __ocml_native_exp2_f32(s[0][2]);
            float e03 = __ocml_native_exp2_f32(s[0][3]);
            float e10 = __ocml_native_exp2_f32(s[1][0]);
            float e11 = __ocml_native_exp2_f32(s[1][1]);
            float e12 = __ocml_native_exp2_f32(s[1][2]);
            float e13 = __ocml_native_exp2_f32(s[1][3]);
            l += ((e00 + e01) + (e02 + e03)) + ((e10 + e11) + (e12 + e13));
            union { unsigned int u[4]; short8 s8; } pk;
            pk.u[0] = pk2(e00, e01); pk.u[1] = pk2(e02, e03);
            pk.u[2] = pk2(e10, e11); pk.u[3] = pk2(e12, e13);
            short8 pa = pk.s8;
            // ---- PV: B-frag = one b128 from vt (permuted V^T) ----
            __builtin_amdgcn_s_setprio(1);                  // T5: MFMA cluster
            #pragma unroll
            for (int dt = 0; dt < 4; dt++) {
                short8 bv = *(const short8*)(vsb + (dt * 16 + lam) * 64 + (((g * 4 + quad) ^ sw) << 3));
                oacc[dt] = __builtin_amdgcn_mfma_f32_16x16x32_bf16(pa, bv, oacc[dt], 0, 0, 0);
            }
            __builtin_amdgcn_s_setprio(0);                  // staging phase next
        }
    };

    // ---- software-pipelined chunk loop: 1 barrier per chunk ----
    gload(0);
    stage(0);
    __syncthreads();
    for (int c = 0; c < 16; ++c) {
        int buf = c & 1;
        if (c < 15) gload(c + 1);      // regs prefetch overlaps compute
        compute(buf);
        if (c < 15) stage(buf ^ 1);    // waits on prefetch, writes other buffer
        __syncthreads();
    }

    // ---- epilogue: reduce l across quads, divide, store f32 ----
    const int b = head >> 4, hh = head & 15;
    {
        float lr = l;
        lr += __shfl_xor(lr, 16);
        lr += __shfl_xor(lr, 32);
        float rl = 1.0f / lr;                    // lane lam holds 1/l for query lam
        float rq[4];
        #pragma unroll
        for (int r = 0; r < 4; r++) rq[r] = __shfl(rl, quad * 4 + r);
        float* ob = out + ((size_t)b * N_ + q0) * (H_ * D_) + hh * 64;
        #pragma unroll
        for (int dt = 0; dt < 4; dt++)
            #pragma unroll
            for (int r = 0; r < 4; r++)
                ob[(quad * 4 + r) * (H_ * D_) + dt * 16 + lam] = oacc[dt][r] * rq[r];
    }
}

extern "C" void kernel_launch(void* const* d_in, const int* in_sizes, int n_in,
                              void* d_out, int out_size, void* d_ws, size_t ws_size,
                              hipStream_t stream) {
    const float* q = (const float*)d_in[0];
    const float* k = (const float*)d_in[1];
    const float* v = (const float*)d_in[2];
    float* out = (float*)d_out;
    (void)d_ws; (void)ws_size;
    hipLaunchKernelGGL(attn_fused, dim3(NH_ * 8), dim3(512), 0, stream, q, k, v, out);
}